// Round 11
// baseline (433.348 us; speedup 1.0000x reference)
//
#include <hip/hip_runtime.h>

typedef short v8s  __attribute__((ext_vector_type(8)));
typedef float v16f __attribute__((ext_vector_type(16)));

#define Wh   1024
#define HWh  (1024 * 512)
#define Wlr  512
#define HWlr (512 * 256)

#define THREADS 512
#define WAVES   8
#define NBLK    512
#define ITERS   4        // 512 blk * 4 it * 8 waves * 32 px = 524288

// LDS: 54 weight A-fragments for 32x32x16 MFMA, 1 KB each (64 lanes x 8 bf16).
// Frag f layout: element (lane l, j): A[m = 32*mt + (l&31)][k = 16*kb + 8*(l>>5) + j]
// Index map: W0: f = mt*8+kb (0..31) | W1: 32 + mt*8+kb (32..47) | W2: 48+kb | W3: 52+kb
#define WF_N 54
#define WFRAG_SHORTS (WF_N * 512)    // 55296 B -> 2 blocks/CU = 110.6 KB

__device__ __forceinline__ unsigned short f2bf(float f) {
    union { float f; unsigned u; } v; v.f = f;
    unsigned r = v.u + 0x7FFFu + ((v.u >> 16) & 1u);  // RNE (cold paths only)
    return (unsigned short)(r >> 16);
}
// hot-path pack: round-half-up bias + v_perm grabbing the two high halves (3 VALU)
__device__ __forceinline__ unsigned pk2(float a, float b) {
    union { float f; unsigned u; } ua, ub;
    ua.f = a; ub.f = b;
    return __builtin_amdgcn_perm(ub.u + 0x8000u, ua.u + 0x8000u, 0x07060302u);
}
__device__ __forceinline__ float leaky(float x) { return fmaxf(x, 0.01f * x); }

// C->B conversion for one next-layer B-frag (32x32 path).
// Inputs: a0,a1 = pd[4g],pd[4g+1] ; b0,b1 = pd[4g+2],pd[4g+3] ; h = lane>>5.
// Frag dwords: d0,d1 = pd[4g],pd[4g+1] taken from the h=0 lane; d2,d3 = pd[4g+2],pd[4g+3]
// from the h=1 lane (same col c). One exchange with lane c^32 carries what the partner needs.
__device__ __forceinline__ v8s convB(unsigned a0, unsigned a1, unsigned b0, unsigned b1, int h) {
    unsigned s0 = h ? a0 : b0;            // what partner needs
    unsigned s1 = h ? a1 : b1;
    unsigned r0 = __shfl_xor(s0, 32, 64);
    unsigned r1 = __shfl_xor(s1, 32, 64);
    union { uint4 u; v8s s; } c;
    c.u.x = h ? r0 : a0;
    c.u.y = h ? r1 : a1;
    c.u.z = h ? b0 : r0;
    c.u.w = h ? b1 : r1;
    return c.s;
}

__global__ __launch_bounds__(THREADS, 4)
void cmfsm_kernel(const float* __restrict__ lr, const float* __restrict__ hr,
                  const float* __restrict__ w0g, const float* __restrict__ w1g,
                  const float* __restrict__ w2g, const float* __restrict__ w3g,
                  const float* __restrict__ w4g, const float* __restrict__ w5g,
                  const float* __restrict__ t0g, const float* __restrict__ t1g,
                  const float* __restrict__ t2g, const float* __restrict__ fwg,
                  float* __restrict__ out)
{
    __shared__ unsigned short wfrag[WFRAG_SHORTS];

    const int tid  = threadIdx.x;
    const int lane = tid & 63;
    const int wv   = tid >> 6;
    const int c    = lane & 31;   // pixel column (stays in-lane through all layers)
    const int h    = lane >> 5;   // k-half selector

    // ---- stage all weights as 32x32x16 A-fragments ----
    for (int e = tid; e < WF_N * 64; e += THREADS) {
        const int f = e >> 6, l = e & 63;
        const int m = l & 31, hs = l >> 5;
        const float* src;
        float zero = 0.f;
        bool valid = true;
        if (f < 32)       { int mt = f >> 3, kb = f & 7;  src = w0g + (32*mt + m)*128 + 16*kb + 8*hs; }
        else if (f < 48)  { int g = f - 32; int mt = g >> 3, kb = g & 7;
                            src = w1g + (32*mt + m)*128 + 16*kb + 8*hs; }
        else if (f < 52)  { int kb = f - 48; src = w2g + m*64 + 16*kb + 8*hs; }
        else              { int kb = f - 52; valid = (m < 16);
                            src = w3g + m*32 + 16*kb + 8*hs; }
        unsigned short* dst = wfrag + f * 512 + l * 8;
#pragma unroll
        for (int j = 0; j < 8; ++j) dst[j] = f2bf(valid ? src[j] : zero);
    }

    // ---- fused layers 4+5 weights for this lane's 8 output rows ----
    // lane holds acc3 regs r=0..7 -> och = (r&3) + 8*(r>>2) + 4*h
    float w45v[8];
#pragma unroll
    for (int r = 0; r < 8; ++r) {
        const int och = (r & 3) + 8 * (r >> 2) + 4 * h;
        float s = 0.f;
#pragma unroll
        for (int j = 0; j < 8; ++j) s += w5g[j] * w4g[j * 16 + och];
        w45v[r] = s;
    }

    // ---- weights2: 4 parity values ----
    float w2tab[4];
#pragma unroll
    for (int yp = 0; yp < 2; ++yp)
#pragma unroll
        for (int xp = 0; xp < 2; ++xp) {
            float i0 = xp ? 1.f : -1.f;
            float i1 = yp ? 1.f : -1.f;
            float i2 = 1.41421356237309505f;
            float h0[3], h1[2];
            for (int o = 0; o < 3; ++o)
                h0[o] = leaky(t0g[o*3+0]*i0 + t0g[o*3+1]*i1 + t0g[o*3+2]*i2);
            for (int o = 0; o < 2; ++o)
                h1[o] = leaky(t1g[o*3+0]*h0[0] + t1g[o*3+1]*h0[1] + t1g[o*3+2]*h0[2]);
            w2tab[yp*2+xp] = t2g[0]*h1[0] + t2g[1]*h1[1];
        }
    const float fa = fabsf(fwg[0]);
    const float fb = fabsf(fwg[1]);

    __syncthreads();   // wfrag ready
    const v16f z16 = (v16f)(0.0f);

    // ---- prefetch slot 0: lane (c,h) loads input ch {8h..8h+7, 16+8h..+7} at px c ----
    float xh[2][8], xl[2][8];
    {
        const int gbase = (blockIdx.x * ITERS * WAVES + wv) * 32;
        const int y = gbase >> 10, x0 = gbase & 1023;
        const float* hb = hr + (size_t)y * Wh + x0 + c;
        const float* lb = lr + (size_t)(y >> 1) * Wlr + (x0 >> 1) + (c >> 1);
#pragma unroll
        for (int b = 0; b < 2; ++b)
#pragma unroll
            for (int j = 0; j < 8; ++j) {
                const int ch = 16 * b + 8 * h + j;
                xh[b][j] = hb[(size_t)ch * HWh];
                xl[b][j] = lb[(size_t)ch * HWlr];
            }
    }

#pragma unroll 1
    for (int it = 0; it < ITERS; ++it) {
        const int gbase = ((blockIdx.x * ITERS + it) * WAVES + wv) * 32;
        const int y = gbase >> 10, x0 = gbase & 1023;

        // ---- build the 8 rep B-frags in registers (pixel = own lane col) ----
        v8s bf[8];
#pragma unroll
        for (int b = 0; b < 2; ++b) {
            unsigned* p0 = (unsigned*)&bf[b];       // lr_up   (rep ch 0-31)
            unsigned* p1 = (unsigned*)&bf[2 + b];   // hr      (32-63)
            unsigned* p2 = (unsigned*)&bf[4 + b];   // product (64-95)
            unsigned* p3 = (unsigned*)&bf[6 + b];   // sq diff (96-127)
#pragma unroll
            for (int d = 0; d < 4; ++d) {
                float l0 = xl[b][2*d], l1 = xl[b][2*d+1];
                float h0 = xh[b][2*d], h1 = xh[b][2*d+1];
                p0[d] = pk2(l0, l1);
                p1[d] = pk2(h0, h1);
                p2[d] = pk2(l0 * h0, l1 * h1);
                float d0 = l0 - h0, d1 = l1 - h1;
                p3[d] = pk2(d0 * d0, d1 * d1);
            }
        }

        // ---- layer 0: 128 -> 128 (4 m-tiles, two at a time), out -> nb1 frags ----
        v8s nb1[8];
#pragma unroll
        for (int mh = 0; mh < 2; ++mh) {
            v16f acc[2];
#pragma unroll
            for (int kb = 0; kb < 8; ++kb) {
#pragma unroll
                for (int t = 0; t < 2; ++t) {
                    v8s a = *(const v8s*)(wfrag + ((2*mh + t) * 8 + kb) * 512 + lane * 8);
                    acc[t] = __builtin_amdgcn_mfma_f32_32x32x16_bf16(
                        a, bf[kb], kb == 0 ? z16 : acc[t], 0, 0, 0);
                }
            }
#pragma unroll
            for (int t = 0; t < 2; ++t) {
                const int mt = 2*mh + t;
                unsigned pd[8];
#pragma unroll
                for (int d = 0; d < 8; ++d)
                    pd[d] = pk2(leaky(acc[t][2*d]), leaky(acc[t][2*d+1]));
                nb1[2*mt + 0] = convB(pd[0], pd[1], pd[2], pd[3], h);
                nb1[2*mt + 1] = convB(pd[4], pd[5], pd[6], pd[7], h);
            }
        }

        // ---- prefetch next slot now (bf dead, xh/xl free to overwrite) ----
        {
            const int nit = (it + 1 < ITERS) ? it + 1 : it;
            const int ng = ((blockIdx.x * ITERS + nit) * WAVES + wv) * 32;
            const int ny = ng >> 10, nx0 = ng & 1023;
            const float* hb = hr + (size_t)ny * Wh + nx0 + c;
            const float* lb = lr + (size_t)(ny >> 1) * Wlr + (nx0 >> 1) + (c >> 1);
#pragma unroll
            for (int b = 0; b < 2; ++b)
#pragma unroll
                for (int j = 0; j < 8; ++j) {
                    const int ch = 16 * b + 8 * h + j;
                    xh[b][j] = hb[(size_t)ch * HWh];
                    xl[b][j] = lb[(size_t)ch * HWlr];
                }
        }

        // ---- layer 1: 128 -> 64 (2 m-tiles) ----
        v8s nb2[4];
        {
            v16f acc[2];
#pragma unroll
            for (int kb = 0; kb < 8; ++kb) {
#pragma unroll
                for (int t = 0; t < 2; ++t) {
                    v8s a = *(const v8s*)(wfrag + (32 + t * 8 + kb) * 512 + lane * 8);
                    acc[t] = __builtin_amdgcn_mfma_f32_32x32x16_bf16(
                        a, nb1[kb], kb == 0 ? z16 : acc[t], 0, 0, 0);
                }
            }
#pragma unroll
            for (int t = 0; t < 2; ++t) {
                unsigned pd[8];
#pragma unroll
                for (int d = 0; d < 8; ++d)
                    pd[d] = pk2(leaky(acc[t][2*d]), leaky(acc[t][2*d+1]));
                nb2[2*t + 0] = convB(pd[0], pd[1], pd[2], pd[3], h);
                nb2[2*t + 1] = convB(pd[4], pd[5], pd[6], pd[7], h);
            }
        }

        // ---- layer 2: 64 -> 32 (1 m-tile) ----
        v8s nb3[2];
        {
            v16f acc;
#pragma unroll
            for (int kb = 0; kb < 4; ++kb) {
                v8s a = *(const v8s*)(wfrag + (48 + kb) * 512 + lane * 8);
                acc = __builtin_amdgcn_mfma_f32_32x32x16_bf16(
                    a, nb2[kb], kb == 0 ? z16 : acc, 0, 0, 0);
            }
            unsigned pd[8];
#pragma unroll
            for (int d = 0; d < 8; ++d)
                pd[d] = pk2(leaky(acc[2*d]), leaky(acc[2*d+1]));
            nb3[0] = convB(pd[0], pd[1], pd[2], pd[3], h);
            nb3[1] = convB(pd[4], pd[5], pd[6], pd[7], h);
        }

        // ---- layer 3: 32 -> 16 (m-padded tile), fused 16->8->1, fuse weights2 ----
        {
            v16f acc;
#pragma unroll
            for (int kb = 0; kb < 2; ++kb) {
                v8s a = *(const v8s*)(wfrag + (52 + kb) * 512 + lane * 8);
                acc = __builtin_amdgcn_mfma_f32_32x32x16_bf16(
                    a, nb3[kb], kb == 0 ? z16 : acc, 0, 0, 0);
            }
            // och rows 0..15 live in regs 0..7 (rows (r&3)+8*(r>>2)+4h); regs 8..15 are pad
            float part = 0.f;
#pragma unroll
            for (int r = 0; r < 8; ++r) part += w45v[r] * leaky(acc[r]);
            part += __shfl_xor(part, 32, 64);
            if (h == 0) {
                out[(size_t)y * Wh + x0 + c] =
                    fa * part + fb * w2tab[((y & 1) << 1) | (c & 1)];
            }
        }
    }
}

extern "C" void kernel_launch(void* const* d_in, const int* in_sizes, int n_in,
                              void* d_out, int out_size, void* d_ws, size_t ws_size,
                              hipStream_t stream) {
    const float* lr  = (const float*)d_in[0];
    const float* hr  = (const float*)d_in[1];
    const float* w0g = (const float*)d_in[2];
    const float* w1g = (const float*)d_in[3];
    const float* w2g = (const float*)d_in[4];
    const float* w3g = (const float*)d_in[5];
    const float* w4g = (const float*)d_in[6];
    const float* w5g = (const float*)d_in[7];
    const float* t0g = (const float*)d_in[8];
    const float* t1g = (const float*)d_in[9];
    const float* t2g = (const float*)d_in[10];
    const float* fwg = (const float*)d_in[11];
    float* out = (float*)d_out;

    hipLaunchKernelGGL(cmfsm_kernel, dim3(NBLK), dim3(THREADS), 0, stream,
                       lr, hr, w0g, w1g, w2g, w3g, w4g, w5g, t0g, t1g, t2g, fwg, out);
}

// Round 12
// 326.747 us; speedup vs baseline: 1.3262x; 1.3262x over previous
//
#include <hip/hip_runtime.h>

typedef short v8s  __attribute__((ext_vector_type(8)));
typedef float v16f __attribute__((ext_vector_type(16)));

#define Wh   1024
#define HWh  (1024 * 512)
#define Wlr  512
#define HWlr (512 * 256)

#define THREADS 512
#define WAVES   8
#define NBLK    512
#define ITERS   4        // 512 blk * 4 it * 8 waves * 32 px = 524288

// LDS: 54 weight A-fragments for 32x32x16 MFMA, 1 KB each (64 lanes x 8 bf16).
// Frag f layout: element (lane l, j): A[m = 32*mt + (l&31)][k = 16*kb + 8*(l>>5) + j]
// Index map: W0: f = mt*8+kb (0..31) | W1: 32 + mt*8+kb (32..47) | W2: 48+kb | W3: 52+kb
// [verified correct end-to-end in round 11: passed, absmax 1.5]
#define WF_N 54
#define WFRAG_SHORTS (WF_N * 512)    // 55296 B

__device__ __forceinline__ unsigned short f2bf(float f) {
    union { float f; unsigned u; } v; v.f = f;
    unsigned r = v.u + 0x7FFFu + ((v.u >> 16) & 1u);  // RNE (cold paths only)
    return (unsigned short)(r >> 16);
}
// hot-path pack: round-half-up bias + v_perm grabbing the two high halves (3 VALU)
__device__ __forceinline__ unsigned pk2(float a, float b) {
    union { float f; unsigned u; } ua, ub;
    ua.f = a; ub.f = b;
    return __builtin_amdgcn_perm(ub.u + 0x8000u, ua.u + 0x8000u, 0x07060302u);
}
__device__ __forceinline__ float leaky(float x) { return fmaxf(x, 0.01f * x); }

// C->B conversion for one next-layer B-frag (32x32 path) — verified round 11.
__device__ __forceinline__ v8s convB(unsigned a0, unsigned a1, unsigned b0, unsigned b1, int h) {
    unsigned s0 = h ? a0 : b0;            // what partner needs
    unsigned s1 = h ? a1 : b1;
    unsigned r0 = __shfl_xor(s0, 32, 64);
    unsigned r1 = __shfl_xor(s1, 32, 64);
    union { uint4 u; v8s s; } c;
    c.u.x = h ? r0 : a0;
    c.u.y = h ? r1 : a1;
    c.u.z = h ? b0 : r0;
    c.u.w = h ? b1 : r1;
    return c.s;
}

// __launch_bounds__(512,2): 256-reg unified cap. Round 11's (512,4)=128 cap forced
// 64 arch + 64 acc and spilled ~40 regs/lane -> 870 MB scratch traffic. Live set
// here is ~150-180 incl. two v16f accumulators -> fits 256, no spill.
__global__ __launch_bounds__(THREADS, 2)
void cmfsm_kernel(const float* __restrict__ lr, const float* __restrict__ hr,
                  const float* __restrict__ w0g, const float* __restrict__ w1g,
                  const float* __restrict__ w2g, const float* __restrict__ w3g,
                  const float* __restrict__ w4g, const float* __restrict__ w5g,
                  const float* __restrict__ t0g, const float* __restrict__ t1g,
                  const float* __restrict__ t2g, const float* __restrict__ fwg,
                  float* __restrict__ out)
{
    __shared__ unsigned short wfrag[WFRAG_SHORTS];

    const int tid  = threadIdx.x;
    const int lane = tid & 63;
    const int wv   = tid >> 6;
    const int c    = lane & 31;   // pixel column (stays in-lane through all layers)
    const int h    = lane >> 5;   // k-half selector

    // ---- stage all weights as 32x32x16 A-fragments ----
    for (int e = tid; e < WF_N * 64; e += THREADS) {
        const int f = e >> 6, l = e & 63;
        const int m = l & 31, hs = l >> 5;
        const float* src;
        bool valid = true;
        if (f < 32)       { int mt = f >> 3, kb = f & 7;  src = w0g + (32*mt + m)*128 + 16*kb + 8*hs; }
        else if (f < 48)  { int g = f - 32; int mt = g >> 3, kb = g & 7;
                            src = w1g + (32*mt + m)*128 + 16*kb + 8*hs; }
        else if (f < 52)  { int kb = f - 48; src = w2g + m*64 + 16*kb + 8*hs; }
        else              { int kb = f - 52; valid = (m < 16);
                            src = w3g + m*32 + 16*kb + 8*hs; }
        unsigned short* dst = wfrag + f * 512 + l * 8;
#pragma unroll
        for (int j = 0; j < 8; ++j) dst[j] = f2bf(valid ? src[j] : 0.f);
    }

    // ---- fused layers 4+5 weights for this lane's 8 output rows ----
    float w45v[8];
#pragma unroll
    for (int r = 0; r < 8; ++r) {
        const int och = (r & 3) + 8 * (r >> 2) + 4 * h;
        float s = 0.f;
#pragma unroll
        for (int j = 0; j < 8; ++j) s += w5g[j] * w4g[j * 16 + och];
        w45v[r] = s;
    }

    // ---- weights2: 4 parity values ----
    float w2tab[4];
#pragma unroll
    for (int yp = 0; yp < 2; ++yp)
#pragma unroll
        for (int xp = 0; xp < 2; ++xp) {
            float i0 = xp ? 1.f : -1.f;
            float i1 = yp ? 1.f : -1.f;
            float i2 = 1.41421356237309505f;
            float h0[3], h1[2];
            for (int o = 0; o < 3; ++o)
                h0[o] = leaky(t0g[o*3+0]*i0 + t0g[o*3+1]*i1 + t0g[o*3+2]*i2);
            for (int o = 0; o < 2; ++o)
                h1[o] = leaky(t1g[o*3+0]*h0[0] + t1g[o*3+1]*h0[1] + t1g[o*3+2]*h0[2]);
            w2tab[yp*2+xp] = t2g[0]*h1[0] + t2g[1]*h1[1];
        }
    const float fa = fabsf(fwg[0]);
    const float fb = fabsf(fwg[1]);

    __syncthreads();   // wfrag ready
    const v16f z16 = (v16f)(0.0f);

    // ---- prefetch slot 0: lane (c,h) loads input ch {8h..8h+7, 16+8h..+7} at px c ----
    float xh[2][8], xl[2][8];
    {
        const int gbase = (blockIdx.x * ITERS * WAVES + wv) * 32;
        const int y = gbase >> 10, x0 = gbase & 1023;
        const float* hb = hr + (size_t)y * Wh + x0 + c;
        const float* lb = lr + (size_t)(y >> 1) * Wlr + (x0 >> 1) + (c >> 1);
#pragma unroll
        for (int b = 0; b < 2; ++b)
#pragma unroll
            for (int j = 0; j < 8; ++j) {
                const int ch = 16 * b + 8 * h + j;
                xh[b][j] = hb[(size_t)ch * HWh];
                xl[b][j] = lb[(size_t)ch * HWlr];
            }
    }

#pragma unroll 1
    for (int it = 0; it < ITERS; ++it) {
        const int gbase = ((blockIdx.x * ITERS + it) * WAVES + wv) * 32;
        const int y = gbase >> 10, x0 = gbase & 1023;

        // ---- build the 8 rep B-frags in registers (pixel = own lane col) ----
        v8s bf[8];
#pragma unroll
        for (int b = 0; b < 2; ++b) {
            unsigned* p0 = (unsigned*)&bf[b];       // lr_up   (rep ch 0-31)
            unsigned* p1 = (unsigned*)&bf[2 + b];   // hr      (32-63)
            unsigned* p2 = (unsigned*)&bf[4 + b];   // product (64-95)
            unsigned* p3 = (unsigned*)&bf[6 + b];   // sq diff (96-127)
#pragma unroll
            for (int d = 0; d < 4; ++d) {
                float l0 = xl[b][2*d], l1 = xl[b][2*d+1];
                float h0 = xh[b][2*d], h1 = xh[b][2*d+1];
                p0[d] = pk2(l0, l1);
                p1[d] = pk2(h0, h1);
                p2[d] = pk2(l0 * h0, l1 * h1);
                float d0 = l0 - h0, d1 = l1 - h1;
                p3[d] = pk2(d0 * d0, d1 * d1);
            }
        }

        // ---- issue next slot's prefetch immediately (xh/xl now dead);
        //      loads stay in flight across all four layers ----
        {
            const int nit = (it + 1 < ITERS) ? it + 1 : it;
            const int ng = ((blockIdx.x * ITERS + nit) * WAVES + wv) * 32;
            const int ny = ng >> 10, nx0 = ng & 1023;
            const float* hb = hr + (size_t)ny * Wh + nx0 + c;
            const float* lb = lr + (size_t)(ny >> 1) * Wlr + (nx0 >> 1) + (c >> 1);
#pragma unroll
            for (int b = 0; b < 2; ++b)
#pragma unroll
                for (int j = 0; j < 8; ++j) {
                    const int ch = 16 * b + 8 * h + j;
                    xh[b][j] = hb[(size_t)ch * HWh];
                    xl[b][j] = lb[(size_t)ch * HWlr];
                }
        }

        // ---- layer 0: 128 -> 128 (4 m-tiles, two at a time), out -> nb1 frags ----
        v8s nb1[8];
#pragma unroll
        for (int mh = 0; mh < 2; ++mh) {
            v16f acc[2];
#pragma unroll
            for (int kb = 0; kb < 8; ++kb) {
#pragma unroll
                for (int t = 0; t < 2; ++t) {
                    v8s a = *(const v8s*)(wfrag + ((2*mh + t) * 8 + kb) * 512 + lane * 8);
                    acc[t] = __builtin_amdgcn_mfma_f32_32x32x16_bf16(
                        a, bf[kb], kb == 0 ? z16 : acc[t], 0, 0, 0);
                }
            }
#pragma unroll
            for (int t = 0; t < 2; ++t) {
                const int mt = 2*mh + t;
                unsigned pd[8];
#pragma unroll
                for (int d = 0; d < 8; ++d)
                    pd[d] = pk2(leaky(acc[t][2*d]), leaky(acc[t][2*d+1]));
                nb1[2*mt + 0] = convB(pd[0], pd[1], pd[2], pd[3], h);
                nb1[2*mt + 1] = convB(pd[4], pd[5], pd[6], pd[7], h);
            }
        }

        // ---- layer 1: 128 -> 64 (2 m-tiles) ----
        v8s nb2[4];
        {
            v16f acc[2];
#pragma unroll
            for (int kb = 0; kb < 8; ++kb) {
#pragma unroll
                for (int t = 0; t < 2; ++t) {
                    v8s a = *(const v8s*)(wfrag + (32 + t * 8 + kb) * 512 + lane * 8);
                    acc[t] = __builtin_amdgcn_mfma_f32_32x32x16_bf16(
                        a, nb1[kb], kb == 0 ? z16 : acc[t], 0, 0, 0);
                }
            }
#pragma unroll
            for (int t = 0; t < 2; ++t) {
                unsigned pd[8];
#pragma unroll
                for (int d = 0; d < 8; ++d)
                    pd[d] = pk2(leaky(acc[t][2*d]), leaky(acc[t][2*d+1]));
                nb2[2*t + 0] = convB(pd[0], pd[1], pd[2], pd[3], h);
                nb2[2*t + 1] = convB(pd[4], pd[5], pd[6], pd[7], h);
            }
        }

        // ---- layer 2: 64 -> 32 (1 m-tile) ----
        v8s nb3[2];
        {
            v16f acc;
#pragma unroll
            for (int kb = 0; kb < 4; ++kb) {
                v8s a = *(const v8s*)(wfrag + (48 + kb) * 512 + lane * 8);
                acc = __builtin_amdgcn_mfma_f32_32x32x16_bf16(
                    a, nb2[kb], kb == 0 ? z16 : acc, 0, 0, 0);
            }
            unsigned pd[8];
#pragma unroll
            for (int d = 0; d < 8; ++d)
                pd[d] = pk2(leaky(acc[2*d]), leaky(acc[2*d+1]));
            nb3[0] = convB(pd[0], pd[1], pd[2], pd[3], h);
            nb3[1] = convB(pd[4], pd[5], pd[6], pd[7], h);
        }

        // ---- layer 3: 32 -> 16 (m-padded tile), fused 16->8->1, fuse weights2 ----
        {
            v16f acc;
#pragma unroll
            for (int kb = 0; kb < 2; ++kb) {
                v8s a = *(const v8s*)(wfrag + (52 + kb) * 512 + lane * 8);
                acc = __builtin_amdgcn_mfma_f32_32x32x16_bf16(
                    a, nb3[kb], kb == 0 ? z16 : acc, 0, 0, 0);
            }
            float part = 0.f;
#pragma unroll
            for (int r = 0; r < 8; ++r) part += w45v[r] * leaky(acc[r]);
            part += __shfl_xor(part, 32, 64);
            if (h == 0) {
                out[(size_t)y * Wh + x0 + c] =
                    fa * part + fb * w2tab[((y & 1) << 1) | (c & 1)];
            }
        }
    }
}

extern "C" void kernel_launch(void* const* d_in, const int* in_sizes, int n_in,
                              void* d_out, int out_size, void* d_ws, size_t ws_size,
                              hipStream_t stream) {
    const float* lr  = (const float*)d_in[0];
    const float* hr  = (const float*)d_in[1];
    const float* w0g = (const float*)d_in[2];
    const float* w1g = (const float*)d_in[3];
    const float* w2g = (const float*)d_in[4];
    const float* w3g = (const float*)d_in[5];
    const float* w4g = (const float*)d_in[6];
    const float* w5g = (const float*)d_in[7];
    const float* t0g = (const float*)d_in[8];
    const float* t1g = (const float*)d_in[9];
    const float* t2g = (const float*)d_in[10];
    const float* fwg = (const float*)d_in[11];
    float* out = (float*)d_out;

    hipLaunchKernelGGL(cmfsm_kernel, dim3(NBLK), dim3(THREADS), 0, stream,
                       lr, hr, w0g, w1g, w2g, w3g, w4g, w5g, t0g, t1g, t2g, fwg, out);
}